// Round 1
// baseline (276.068 us; speedup 1.0000x reference)
//
#include <hip/hip_runtime.h>
#include <math.h>

#define N_COLS 1024
#define NRINGS 8

// ---- geometry: 64 lanes/row (full wave), 16 cols/thread, 1 row/thread ----
#define TPR    64
#define CHUNK  16
#define ROWS_PER_BLOCK 8          // 512 threads / 64 lanes-per-row

// ws layout (floats)
#define F_OFF   16384             // CS: 8 rings * 512 float4 = 16384 floats (64 KB)
#define A_OFF   24576             // F : 8 rings * 256 float4 =  8192 floats (32 KB)
#define AUX_OFF 25088             // A : 8 rings * 64 floats  =   512 floats
#define WS_FLOATS 25104           // AUX: 8 float2

// address-space-qualified pointer types for global_load_lds
typedef const __attribute__((address_space(1))) float4* gas_f4;
typedef __attribute__((address_space(3))) void* las_ptr;

// =====================  setup: build angle tables  ======================
// grid = 32 blocks (4 per ring, 256 angles each). 1 sincos per thread.
//   CS  [(r*8 + jp)*64 + t] : float4 (c_j0,s_j0,c_j1,s_j1), k = t*16 + 2*jp
//   F   [(r*4 + q )*64 + t] : float4 f_j = c_j * prod_{l>j in chunk}(-s_l)
//   A   [r*64 + t]          : prod_j(-s_j) over chunk t
//   AUX [r]                 : real (c,s) at k=1023 (table entry doctored to
//                             (0,-1) = exact no-op chain step)
__global__ __launch_bounds__(256)
void ced_setup(const float* __restrict__ ae,
               const float* __restrict__ ad,
               float* __restrict__ ws)
{
    __shared__ float2 ls[256];
    const int r   = blockIdx.x >> 2;
    const int b   = blockIdx.x & 3;
    const int tid = threadIdx.x;
    const int k   = (b << 8) + tid;           // t = k>>4, j = k&15
    const float* ang = (r < 4) ? (ae + (r << 10)) : (ad + ((r - 4) << 10));

    float sv, cv;
    sincosf(ang[k], &sv, &cv);
    if (k == N_COLS - 1) {
        ((float2*)(ws + AUX_OFF))[r] = make_float2(cv, sv);
        cv = 0.f; sv = -1.f;                  // doctored: no-op step
    }
    ls[tid] = make_float2(cv, sv);
    __syncthreads();

    if (!(tid & 1)) {                         // paired (c,s) table
        float2 e0 = ls[tid], e1 = ls[tid + 1];
        int t  = k >> 4;
        int jp = (k & 15) >> 1;
        ((float4*)ws)[(r*8 + jp)*64 + t] = make_float4(e0.x, e0.y, e1.x, e1.y);
    }

    if (tid < 64) {                           // F and A via 2-round shfl product-scan
        const int lt = tid >> 2;              // local chunk 0..15
        const int q  = tid & 3;               // 4-element sub-segment 0..3
        const int t  = (b << 4) + lt;         // global chunk 0..63
        const int j0 = lt * CHUNK + 4 * q;
        float2 e0 = ls[j0], e1 = ls[j0+1], e2 = ls[j0+2], e3 = ls[j0+3];

        float f3 = e3.x;       float P = -e3.y;
        float f2 = e2.x * P;   P *= -e2.y;
        float f1 = e1.x * P;   P *= -e1.y;
        float f0 = e0.x * P;   P *= -e0.y;

        float ip = P;                         // inclusive suffix product over segments
        #pragma unroll
        for (int d = 1; d < 4; d <<= 1) {
            float tmp = __shfl_down(ip, d);
            if (q + d < 4) ip *= tmp;
        }
        float ex = __shfl_down(ip, 1);
        if (q == 3) ex = 1.f;
        f0 *= ex; f1 *= ex; f2 *= ex; f3 *= ex;

        ((float4*)(ws + F_OFF))[(r*4 + q)*64 + t] = make_float4(f0, f1, f2, f3);
        if (q == 0) ws[A_OFF + r*TPR + t] = ip;
    }
}

// =====================  main: fused enc->blend->dec  ====================
// R5 theory: 2-rows/thread geometry caps the grid at 512 blocks = 2 blocks/CU
// (8 waves/CU) -> latency-bound at 25% HBM / 20% VALU. Re-partition to
// 1 row per full wave (64 lanes x 16 cols): 1024 blocks x 512 thr, single-ring
// double-buffered LDS staging (26 KB) -> 4 blocks/CU = 32 waves/CU. Carry
// chain halves (16 dep FMA/ring); scan is 6 shfl rounds over 64 lanes.
__global__ __launch_bounds__(512, 8)
void ced_main(const float* __restrict__ x,
              const float* __restrict__ ws,
              const float* __restrict__ hw,
              const float* __restrict__ hs,
              float* __restrict__ out, int B)
{
    __shared__ float4 sCS[2][512];    // 2 bufs x (1 ring x 512 float4) = 16 KB
    __shared__ float4 sF [2][256];    // 2 bufs x (1 ring x 256 float4) =  8 KB
    __shared__ float4 sA4[128];       // A: 8*64 floats = 2 KB
    __shared__ float4 sAux4[4];       // AUX: 8 float2

    const float4* CSg = (const float4*)ws;
    const float4* Fg  = (const float4*)(ws + F_OFF);

    const int tid = threadIdx.x;
    const int t   = tid & 63;                        // chunk index within row
    const int row = blockIdx.x * ROWS_PER_BLOCK + (tid >> 6);
    const size_t rowOff = (size_t)row * N_COLS;

    // ---- stage ring 0 into buf 0 (async, drained by first sync) ----
    __builtin_amdgcn_global_load_lds((gas_f4)(CSg + tid),
                                     (las_ptr)&sCS[0][tid], 16, 0, 0);
    if (tid < 256)
        __builtin_amdgcn_global_load_lds((gas_f4)(Fg + tid),
                                         (las_ptr)&sF[0][tid], 16, 0, 0);

    // ---- stage A + AUX (once) ----
    if (tid < 128)                sA4[tid]         = ((const float4*)(ws + A_OFF))[tid];
    if (tid >= 128 && tid < 132)  sAux4[tid - 128] = ((const float4*)(ws + AUX_OFF))[tid - 128];

    // ---- load x (1 row, 16 cols) ----
    float y[CHUNK];
    {
        const float4* xp = (const float4*)(x + rowOff + t * CHUNK);
        #pragma unroll
        for (int i = 0; i < 4; ++i) {
            float4 v = xp[i];
            y[4*i] = v.x; y[4*i+1] = v.y; y[4*i+2] = v.z; y[4*i+3] = v.w;
        }
    }

    const float w   = 1.f / (1.f + expf(-hw[0]));
    const float omw = 1.f - w;

    __syncthreads();                  // stage0 + A/AUX visible to all waves

    const float*  As   = (const float*)sA4;
    const float2* Auxs = (const float2*)sAux4;

    #pragma unroll 1
    for (int r = 0; r < NRINGS; ++r) {
        // ---- issue stage(r+1) into the other buffer (async) ----
        if (r < NRINGS - 1) {
            const int nb = (r + 1) & 1;
            __builtin_amdgcn_global_load_lds((gas_f4)(CSg + (r + 1) * 512 + tid),
                                             (las_ptr)&sCS[nb][tid], 16, 0, 0);
            if (tid < 256)
                __builtin_amdgcn_global_load_lds((gas_f4)(Fg + (r + 1) * 256 + tid),
                                                 (las_ptr)&sF[nb][tid], 16, 0, 0);
        }

        if (r == 4) {                 // bottleneck blend + output 0
            float4* oa = (float4*)(out + rowOff + t * CHUNK);
            const float4* hp = (const float4*)(hs + t * CHUNK);
            #pragma unroll
            for (int i = 0; i < 4; ++i) {
                float4 h = hp[i];
                float4 nb2;
                nb2.x = fmaf(omw, y[4*i+0], w * h.x);
                nb2.y = fmaf(omw, y[4*i+1], w * h.y);
                nb2.z = fmaf(omw, y[4*i+2], w * h.z);
                nb2.w = fmaf(omw, y[4*i+3], w * h.w);
                oa[i] = nb2;
                y[4*i+0] = nb2.x; y[4*i+1] = nb2.y; y[4*i+2] = nb2.z; y[4*i+3] = nb2.w;
            }
        }

        const int buf = r & 1;
        const float4* csL = &sCS[buf][0];          // + jp*64 + t
        const float4* fL  = &sF [buf][0];          // + qi*64 + t
        const float2  cN  = Auxs[r];
        const float   saI = As[r * TPR + t];

        float y0 = __shfl(y[0],       0);
        float yN = __shfl(y[CHUNK-1], 63);
        float Cinit = cN.x * yN - cN.y * y0;
        float x0n   = fmaf(cN.y, yN, cN.x * y0);
        if (t == 0) y[0] = x0n;

        // ---- pass 1: local chain (carry_in = 0) ----
        float car = 0.f, zt = 0.f;
        #pragma unroll
        for (int jp = CHUNK/2 - 1; jp >= 0; --jp) {
            float4 cs4 = csL[jp * 64 + t];         // (c_j0,s_j0,c_j1,s_j1)
            const int j1 = 2*jp + 1;
            float z1 = fmaf(cs4.w, y[j1], cs4.z * car);
            car = fmaf(-cs4.w, car, cs4.z * y[j1]);
            if (j1 == CHUNK - 1) zt = z1;
            else                 y[j1+1] = z1;
            const int j0 = 2*jp;
            float z0 = fmaf(cs4.y, y[j0], cs4.x * car);
            car = fmaf(-cs4.y, car, cs4.x * y[j0]);
            y[j0+1] = z0;
        }

        // ---- affine suffix scan over 64 lanes ----
        float sa = saI, sb = car;
        #pragma unroll
        for (int d = 1; d < TPR; d <<= 1) {
            float a2 = __shfl_down(sa, d);
            float b2 = __shfl_down(sb, d);
            if (t + d < TPR) { sb = fmaf(sa, b2, sb); sa *= a2; }
        }
        float ea = __shfl_down(sa, 1);
        float eb = __shfl_down(sb, 1);
        float zf  = fmaf(sa, Cinit, sb);           // lane0: final z[0]
        float Cin = (t == TPR - 1) ? Cinit : fmaf(ea, Cinit, eb);

        // ---- pass 2: independent fix-up with precomputed f ----
        #pragma unroll
        for (int qi = CHUNK/4 - 1; qi >= 0; --qi) {
            float4 f4 = fL[qi * 64 + t];
            const int j = 4*qi;
            if (j + 3 == CHUNK - 1) zt = fmaf(f4.w, Cin, zt);
            else                    y[j+4] = fmaf(f4.w, Cin, y[j+4]);
            y[j+3] = fmaf(f4.z, Cin, y[j+3]);
            y[j+2] = fmaf(f4.y, Cin, y[j+2]);
            y[j+1] = fmaf(f4.x, Cin, y[j+1]);
        }

        float up = __shfl_up(zt, 1);               // lane t-1's top -> slot 16t
        y[0] = (t == 0) ? zf : up;

        // ring boundary: drains stage(r+1) + protects buffer reuse
        if (r < NRINGS - 1) __syncthreads();
    }

    float4* oo = (float4*)(out + (size_t)B * N_COLS + rowOff + t * CHUNK);
    #pragma unroll
    for (int i = 0; i < 4; ++i)
        oo[i] = make_float4(y[4*i], y[4*i+1], y[4*i+2], y[4*i+3]);
}

// ==================  fallback (self-contained, ws-free)  =================
__global__ __launch_bounds__(256, 2)
void ced_fallback(const float* __restrict__ x,
                  const float* __restrict__ ae,
                  const float* __restrict__ ad,
                  const float* __restrict__ hw,
                  const float* __restrict__ hs,
                  float* __restrict__ out, int B)
{
    __shared__ float2 s_cs[NRINGS * 64 * 16];
    __shared__ float  s_A [NRINGS * 16];
    __shared__ float2 s_aux[NRINGS];

    const int tid = threadIdx.x;
    for (int i = 0; i < 32; ++i) {
        int idx = i * 256 + tid;
        int r   = idx >> 10;
        int k   = idx & 1023;
        const float* ang = (r < 4) ? (ae + (r << 10)) : (ad + ((r - 4) << 10));
        float sv, cv;
        sincosf(ang[k], &sv, &cv);
        int t = k >> 6, j = k & 63;
        float2 e = make_float2(cv, sv);
        if (k == 1023) { s_aux[r] = e; e = make_float2(0.f, -1.f); }
        s_cs[(r * 64 + j) * 16 + t] = e;
    }
    __syncthreads();
    if (tid < NRINGS * 16) {
        int r = tid >> 4, t = tid & 15;
        float p = 1.f;
        for (int j = 0; j < 64; ++j) p *= -s_cs[(r * 64 + j) * 16 + t].y;
        s_A[tid] = p;
    }
    __syncthreads();

    const int lane      = tid & 63;
    const int g         = lane >> 4;
    const int t         = lane & 15;
    const int groupBase = lane & 48;
    const int row       = blockIdx.x * 16 + (tid >> 6) * 4 + g;

    const float* xr = x + (size_t)row * N_COLS + t * 64;
    float y[64];
    #pragma unroll
    for (int i = 0; i < 16; ++i) {
        float4 v = ((const float4*)xr)[i];
        y[4*i] = v.x; y[4*i+1] = v.y; y[4*i+2] = v.z; y[4*i+3] = v.w;
    }
    const float w   = 1.f / (1.f + expf(-hw[0]));
    const float omw = 1.f - w;

    for (int r = 0; r < NRINGS; ++r) {
        if (r == 4) {
            float4* ob = (float4*)(out + (size_t)row * N_COLS + t * 64);
            const float4* hp = (const float4*)(hs + t * 64);
            #pragma unroll
            for (int i = 0; i < 16; ++i) {
                float4 h = hp[i];
                float4 bn;
                bn.x = fmaf(omw, y[4*i+0], w * h.x);
                bn.y = fmaf(omw, y[4*i+1], w * h.y);
                bn.z = fmaf(omw, y[4*i+2], w * h.z);
                bn.w = fmaf(omw, y[4*i+3], w * h.w);
                ob[i] = bn;
                y[4*i+0] = bn.x; y[4*i+1] = bn.y; y[4*i+2] = bn.z; y[4*i+3] = bn.w;
            }
        }
        const float2* csr = s_cs + r * 64 * 16;
        const float2  cN  = s_aux[r];
        float y0 = __shfl(y[0],  groupBase);
        float yN = __shfl(y[63], groupBase + 15);
        float Cinit = cN.x * yN - cN.y * y0;
        float x0n   = fmaf(cN.y, yN, cN.x * y0);
        if (t == 0) y[0] = x0n;

        float carry = 0.f, ztmp = 0.f;
        #pragma unroll
        for (int j = 63; j >= 0; --j) {
            float2 cs = csr[j * 16 + t];
            float z   = fmaf(cs.y, y[j], cs.x * carry);
            carry     = fmaf(-cs.y, carry, cs.x * y[j]);
            if (j == 63) ztmp = z; else y[j + 1] = z;
        }
        float sa = s_A[r * 16 + t], sb = carry;
        #pragma unroll
        for (int d = 1; d < 16; d <<= 1) {
            float a2 = __shfl_down(sa, d);
            float b2 = __shfl_down(sb, d);
            if (t + d < 16) { sb = fmaf(sa, b2, sb); sa *= a2; }
        }
        float ea = __shfl_down(sa, 1);
        float eb = __shfl_down(sb, 1);
        float z0  = fmaf(sa, Cinit, sb);
        float Cin = (t == 15) ? Cinit : fmaf(ea, Cinit, eb);

        float P = 1.f;
        #pragma unroll
        for (int j = 63; j >= 0; --j) {
            float2 cs = csr[j * 16 + t];
            float f = cs.x * P;
            P = -cs.y * P;
            if (j == 63) ztmp = fmaf(f, Cin, ztmp);
            else         y[j + 1] = fmaf(f, Cin, y[j + 1]);
        }
        float up = __shfl_up(ztmp, 1);
        y[0] = (t == 0) ? z0 : up;
    }

    float4* oo = (float4*)(out + (size_t)B * N_COLS + (size_t)row * N_COLS + t * 64);
    #pragma unroll
    for (int i = 0; i < 16; ++i)
        oo[i] = make_float4(y[4*i], y[4*i+1], y[4*i+2], y[4*i+3]);
}

// ============================  launcher  ================================
extern "C" void kernel_launch(void* const* d_in, const int* in_sizes, int n_in,
                              void* d_out, int out_size, void* d_ws, size_t ws_size,
                              hipStream_t stream) {
    const float* x  = (const float*)d_in[0];
    const float* ae = (const float*)d_in[1];
    const float* ad = (const float*)d_in[2];
    const float* hw = (const float*)d_in[3];
    const float* hs = (const float*)d_in[4];
    float* out = (float*)d_out;
    const int B = in_sizes[0] / N_COLS;          // 8192

    if (ws_size >= WS_FLOATS * sizeof(float) && (B % ROWS_PER_BLOCK) == 0) {
        hipLaunchKernelGGL(ced_setup, dim3(32), dim3(256), 0, stream,
                           ae, ad, (float*)d_ws);
        hipLaunchKernelGGL(ced_main, dim3(B / ROWS_PER_BLOCK), dim3(512), 0, stream,
                           x, (const float*)d_ws, hw, hs, out, B);
    } else {
        hipLaunchKernelGGL(ced_fallback, dim3(B / 16), dim3(256), 0, stream,
                           x, ae, ad, hw, hs, out, B);
    }
}

// Round 2
// 129.328 us; speedup vs baseline: 2.1346x; 2.1346x over previous
//
#include <hip/hip_runtime.h>
#include <math.h>

#define N_COLS 1024
#define NRINGS 8

// ---- geometry: 64 lanes/row (full wave), 16 cols/thread, 1 row/thread ----
#define TPR    64
#define CHUNK  16
#define ROWS_PER_BLOCK 8          // 512 threads / 64 lanes-per-row

// ws layout (floats)
#define F_OFF   16384             // CS: 8 rings * 512 float4 = 16384 floats (64 KB)
#define A_OFF   24576             // F : 8 rings * 256 float4 =  8192 floats (32 KB)
#define AUX_OFF 25088             // A : 8 rings * 64 floats  =   512 floats
#define WS_FLOATS 25104           // AUX: 8 float2

// address-space-qualified pointer types for global_load_lds
typedef const __attribute__((address_space(1))) float4* gas_f4;
typedef __attribute__((address_space(3))) void* las_ptr;

// =====================  setup: build angle tables  ======================
// grid = 32 blocks (4 per ring, 256 angles each). 1 sincos per thread.
//   CS  [(r*8 + jp)*64 + t] : float4 (c_j0,s_j0,c_j1,s_j1), k = t*16 + 2*jp
//   F   [(r*4 + q )*64 + t] : float4 f_j = c_j * prod_{l>j in chunk}(-s_l)
//   A   [r*64 + t]          : prod_j(-s_j) over chunk t
//   AUX [r]                 : real (c,s) at k=1023 (table entry doctored to
//                             (0,-1) = exact no-op chain step)
__global__ __launch_bounds__(256)
void ced_setup(const float* __restrict__ ae,
               const float* __restrict__ ad,
               float* __restrict__ ws)
{
    __shared__ float2 ls[256];
    const int r   = blockIdx.x >> 2;
    const int b   = blockIdx.x & 3;
    const int tid = threadIdx.x;
    const int k   = (b << 8) + tid;           // t = k>>4, j = k&15
    const float* ang = (r < 4) ? (ae + (r << 10)) : (ad + ((r - 4) << 10));

    float sv, cv;
    sincosf(ang[k], &sv, &cv);
    if (k == N_COLS - 1) {
        ((float2*)(ws + AUX_OFF))[r] = make_float2(cv, sv);
        cv = 0.f; sv = -1.f;                  // doctored: no-op step
    }
    ls[tid] = make_float2(cv, sv);
    __syncthreads();

    if (!(tid & 1)) {                         // paired (c,s) table
        float2 e0 = ls[tid], e1 = ls[tid + 1];
        int t  = k >> 4;
        int jp = (k & 15) >> 1;
        ((float4*)ws)[(r*8 + jp)*64 + t] = make_float4(e0.x, e0.y, e1.x, e1.y);
    }

    if (tid < 64) {                           // F and A via 2-round shfl product-scan
        const int lt = tid >> 2;              // local chunk 0..15
        const int q  = tid & 3;               // 4-element sub-segment 0..3
        const int t  = (b << 4) + lt;         // global chunk 0..63
        const int j0 = lt * CHUNK + 4 * q;
        float2 e0 = ls[j0], e1 = ls[j0+1], e2 = ls[j0+2], e3 = ls[j0+3];

        float f3 = e3.x;       float P = -e3.y;
        float f2 = e2.x * P;   P *= -e2.y;
        float f1 = e1.x * P;   P *= -e1.y;
        float f0 = e0.x * P;   P *= -e0.y;

        float ip = P;                         // inclusive suffix product over segments
        #pragma unroll
        for (int d = 1; d < 4; d <<= 1) {
            float tmp = __shfl_down(ip, d);
            if (q + d < 4) ip *= tmp;
        }
        float ex = __shfl_down(ip, 1);
        if (q == 3) ex = 1.f;
        f0 *= ex; f1 *= ex; f2 *= ex; f3 *= ex;

        ((float4*)(ws + F_OFF))[(r*4 + q)*64 + t] = make_float4(f0, f1, f2, f3);
        if (q == 0) ws[A_OFF + r*TPR + t] = ip;
    }
}

// =====================  main: fused enc->blend->dec  ====================
// R5 post-mortem: __launch_bounds__(512,8) capped VGPR at 32 -> ~750 MB of
// scratch spill traffic (FETCH 348MB / WRITE 570MB vs 93MB ideal), 199us.
// R6: relax to (512,4): VGPR cap 128, kernel fits (~64-90) with zero spill,
// 16 waves/CU = 2x the R4 baseline's 8. Geometry unchanged: 1 row per full
// wave (64 lanes x 16 cols), single-ring double-buffered async LDS staging.
__global__ __launch_bounds__(512, 4)
void ced_main(const float* __restrict__ x,
              const float* __restrict__ ws,
              const float* __restrict__ hw,
              const float* __restrict__ hs,
              float* __restrict__ out, int B)
{
    __shared__ float4 sCS[2][512];    // 2 bufs x (1 ring x 512 float4) = 16 KB
    __shared__ float4 sF [2][256];    // 2 bufs x (1 ring x 256 float4) =  8 KB
    __shared__ float4 sA4[128];       // A: 8*64 floats = 2 KB
    __shared__ float4 sAux4[4];       // AUX: 8 float2

    const float4* CSg = (const float4*)ws;
    const float4* Fg  = (const float4*)(ws + F_OFF);

    const int tid = threadIdx.x;
    const int t   = tid & 63;                        // chunk index within row
    const int row = blockIdx.x * ROWS_PER_BLOCK + (tid >> 6);
    const size_t rowOff = (size_t)row * N_COLS;

    // ---- stage ring 0 into buf 0 (async, drained by first sync) ----
    __builtin_amdgcn_global_load_lds((gas_f4)(CSg + tid),
                                     (las_ptr)&sCS[0][tid], 16, 0, 0);
    if (tid < 256)
        __builtin_amdgcn_global_load_lds((gas_f4)(Fg + tid),
                                         (las_ptr)&sF[0][tid], 16, 0, 0);

    // ---- stage A + AUX (once) ----
    if (tid < 128)                sA4[tid]         = ((const float4*)(ws + A_OFF))[tid];
    if (tid >= 128 && tid < 132)  sAux4[tid - 128] = ((const float4*)(ws + AUX_OFF))[tid - 128];

    // ---- load x (1 row, 16 cols) ----
    float y[CHUNK];
    {
        const float4* xp = (const float4*)(x + rowOff + t * CHUNK);
        #pragma unroll
        for (int i = 0; i < 4; ++i) {
            float4 v = xp[i];
            y[4*i] = v.x; y[4*i+1] = v.y; y[4*i+2] = v.z; y[4*i+3] = v.w;
        }
    }

    const float w   = 1.f / (1.f + expf(-hw[0]));
    const float omw = 1.f - w;

    __syncthreads();                  // stage0 + A/AUX visible to all waves

    const float*  As   = (const float*)sA4;
    const float2* Auxs = (const float2*)sAux4;

    #pragma unroll 1
    for (int r = 0; r < NRINGS; ++r) {
        // ---- issue stage(r+1) into the other buffer (async) ----
        if (r < NRINGS - 1) {
            const int nb = (r + 1) & 1;
            __builtin_amdgcn_global_load_lds((gas_f4)(CSg + (r + 1) * 512 + tid),
                                             (las_ptr)&sCS[nb][tid], 16, 0, 0);
            if (tid < 256)
                __builtin_amdgcn_global_load_lds((gas_f4)(Fg + (r + 1) * 256 + tid),
                                                 (las_ptr)&sF[nb][tid], 16, 0, 0);
        }

        if (r == 4) {                 // bottleneck blend + output 0
            float4* oa = (float4*)(out + rowOff + t * CHUNK);
            const float4* hp = (const float4*)(hs + t * CHUNK);
            #pragma unroll
            for (int i = 0; i < 4; ++i) {
                float4 h = hp[i];
                float4 nb2;
                nb2.x = fmaf(omw, y[4*i+0], w * h.x);
                nb2.y = fmaf(omw, y[4*i+1], w * h.y);
                nb2.z = fmaf(omw, y[4*i+2], w * h.z);
                nb2.w = fmaf(omw, y[4*i+3], w * h.w);
                oa[i] = nb2;
                y[4*i+0] = nb2.x; y[4*i+1] = nb2.y; y[4*i+2] = nb2.z; y[4*i+3] = nb2.w;
            }
        }

        const int buf = r & 1;
        const float4* csL = &sCS[buf][0];          // + jp*64 + t
        const float4* fL  = &sF [buf][0];          // + qi*64 + t
        const float2  cN  = Auxs[r];
        const float   saI = As[r * TPR + t];

        float y0 = __shfl(y[0],       0);
        float yN = __shfl(y[CHUNK-1], 63);
        float Cinit = cN.x * yN - cN.y * y0;
        float x0n   = fmaf(cN.y, yN, cN.x * y0);
        if (t == 0) y[0] = x0n;

        // ---- pass 1: local chain (carry_in = 0) ----
        float car = 0.f, zt = 0.f;
        #pragma unroll
        for (int jp = CHUNK/2 - 1; jp >= 0; --jp) {
            float4 cs4 = csL[jp * 64 + t];         // (c_j0,s_j0,c_j1,s_j1)
            const int j1 = 2*jp + 1;
            float z1 = fmaf(cs4.w, y[j1], cs4.z * car);
            car = fmaf(-cs4.w, car, cs4.z * y[j1]);
            if (j1 == CHUNK - 1) zt = z1;
            else                 y[j1+1] = z1;
            const int j0 = 2*jp;
            float z0 = fmaf(cs4.y, y[j0], cs4.x * car);
            car = fmaf(-cs4.y, car, cs4.x * y[j0]);
            y[j0+1] = z0;
        }

        // ---- affine suffix scan over 64 lanes ----
        float sa = saI, sb = car;
        #pragma unroll
        for (int d = 1; d < TPR; d <<= 1) {
            float a2 = __shfl_down(sa, d);
            float b2 = __shfl_down(sb, d);
            if (t + d < TPR) { sb = fmaf(sa, b2, sb); sa *= a2; }
        }
        float ea = __shfl_down(sa, 1);
        float eb = __shfl_down(sb, 1);
        float zf  = fmaf(sa, Cinit, sb);           // lane0: final z[0]
        float Cin = (t == TPR - 1) ? Cinit : fmaf(ea, Cinit, eb);

        // ---- pass 2: independent fix-up with precomputed f ----
        #pragma unroll
        for (int qi = CHUNK/4 - 1; qi >= 0; --qi) {
            float4 f4 = fL[qi * 64 + t];
            const int j = 4*qi;
            if (j + 3 == CHUNK - 1) zt = fmaf(f4.w, Cin, zt);
            else                    y[j+4] = fmaf(f4.w, Cin, y[j+4]);
            y[j+3] = fmaf(f4.z, Cin, y[j+3]);
            y[j+2] = fmaf(f4.y, Cin, y[j+2]);
            y[j+1] = fmaf(f4.x, Cin, y[j+1]);
        }

        float up = __shfl_up(zt, 1);               // lane t-1's top -> slot 16t
        y[0] = (t == 0) ? zf : up;

        // ring boundary: drains stage(r+1) + protects buffer reuse
        if (r < NRINGS - 1) __syncthreads();
    }

    float4* oo = (float4*)(out + (size_t)B * N_COLS + rowOff + t * CHUNK);
    #pragma unroll
    for (int i = 0; i < 4; ++i)
        oo[i] = make_float4(y[4*i], y[4*i+1], y[4*i+2], y[4*i+3]);
}

// ==================  fallback (self-contained, ws-free)  =================
__global__ __launch_bounds__(256, 2)
void ced_fallback(const float* __restrict__ x,
                  const float* __restrict__ ae,
                  const float* __restrict__ ad,
                  const float* __restrict__ hw,
                  const float* __restrict__ hs,
                  float* __restrict__ out, int B)
{
    __shared__ float2 s_cs[NRINGS * 64 * 16];
    __shared__ float  s_A [NRINGS * 16];
    __shared__ float2 s_aux[NRINGS];

    const int tid = threadIdx.x;
    for (int i = 0; i < 32; ++i) {
        int idx = i * 256 + tid;
        int r   = idx >> 10;
        int k   = idx & 1023;
        const float* ang = (r < 4) ? (ae + (r << 10)) : (ad + ((r - 4) << 10));
        float sv, cv;
        sincosf(ang[k], &sv, &cv);
        int t = k >> 6, j = k & 63;
        float2 e = make_float2(cv, sv);
        if (k == 1023) { s_aux[r] = e; e = make_float2(0.f, -1.f); }
        s_cs[(r * 64 + j) * 16 + t] = e;
    }
    __syncthreads();
    if (tid < NRINGS * 16) {
        int r = tid >> 4, t = tid & 15;
        float p = 1.f;
        for (int j = 0; j < 64; ++j) p *= -s_cs[(r * 64 + j) * 16 + t].y;
        s_A[tid] = p;
    }
    __syncthreads();

    const int lane      = tid & 63;
    const int g         = lane >> 4;
    const int t         = lane & 15;
    const int groupBase = lane & 48;
    const int row       = blockIdx.x * 16 + (tid >> 6) * 4 + g;

    const float* xr = x + (size_t)row * N_COLS + t * 64;
    float y[64];
    #pragma unroll
    for (int i = 0; i < 16; ++i) {
        float4 v = ((const float4*)xr)[i];
        y[4*i] = v.x; y[4*i+1] = v.y; y[4*i+2] = v.z; y[4*i+3] = v.w;
    }
    const float w   = 1.f / (1.f + expf(-hw[0]));
    const float omw = 1.f - w;

    for (int r = 0; r < NRINGS; ++r) {
        if (r == 4) {
            float4* ob = (float4*)(out + (size_t)row * N_COLS + t * 64);
            const float4* hp = (const float4*)(hs + t * 64);
            #pragma unroll
            for (int i = 0; i < 16; ++i) {
                float4 h = hp[i];
                float4 bn;
                bn.x = fmaf(omw, y[4*i+0], w * h.x);
                bn.y = fmaf(omw, y[4*i+1], w * h.y);
                bn.z = fmaf(omw, y[4*i+2], w * h.z);
                bn.w = fmaf(omw, y[4*i+3], w * h.w);
                ob[i] = bn;
                y[4*i+0] = bn.x; y[4*i+1] = bn.y; y[4*i+2] = bn.z; y[4*i+3] = bn.w;
            }
        }
        const float2* csr = s_cs + r * 64 * 16;
        const float2  cN  = s_aux[r];
        float y0 = __shfl(y[0],  groupBase);
        float yN = __shfl(y[63], groupBase + 15);
        float Cinit = cN.x * yN - cN.y * y0;
        float x0n   = fmaf(cN.y, yN, cN.x * y0);
        if (t == 0) y[0] = x0n;

        float carry = 0.f, ztmp = 0.f;
        #pragma unroll
        for (int j = 63; j >= 0; --j) {
            float2 cs = csr[j * 16 + t];
            float z   = fmaf(cs.y, y[j], cs.x * carry);
            carry     = fmaf(-cs.y, carry, cs.x * y[j]);
            if (j == 63) ztmp = z; else y[j + 1] = z;
        }
        float sa = s_A[r * 16 + t], sb = carry;
        #pragma unroll
        for (int d = 1; d < 16; d <<= 1) {
            float a2 = __shfl_down(sa, d);
            float b2 = __shfl_down(sb, d);
            if (t + d < 16) { sb = fmaf(sa, b2, sb); sa *= a2; }
        }
        float ea = __shfl_down(sa, 1);
        float eb = __shfl_down(sb, 1);
        float z0  = fmaf(sa, Cinit, sb);
        float Cin = (t == 15) ? Cinit : fmaf(ea, Cinit, eb);

        float P = 1.f;
        #pragma unroll
        for (int j = 63; j >= 0; --j) {
            float2 cs = csr[j * 16 + t];
            float f = cs.x * P;
            P = -cs.y * P;
            if (j == 63) ztmp = fmaf(f, Cin, ztmp);
            else         y[j + 1] = fmaf(f, Cin, y[j + 1]);
        }
        float up = __shfl_up(ztmp, 1);
        y[0] = (t == 0) ? z0 : up;
    }

    float4* oo = (float4*)(out + (size_t)B * N_COLS + (size_t)row * N_COLS + t * 64);
    #pragma unroll
    for (int i = 0; i < 16; ++i)
        oo[i] = make_float4(y[4*i], y[4*i+1], y[4*i+2], y[4*i+3]);
}

// ============================  launcher  ================================
extern "C" void kernel_launch(void* const* d_in, const int* in_sizes, int n_in,
                              void* d_out, int out_size, void* d_ws, size_t ws_size,
                              hipStream_t stream) {
    const float* x  = (const float*)d_in[0];
    const float* ae = (const float*)d_in[1];
    const float* ad = (const float*)d_in[2];
    const float* hw = (const float*)d_in[3];
    const float* hs = (const float*)d_in[4];
    float* out = (float*)d_out;
    const int B = in_sizes[0] / N_COLS;          // 8192

    if (ws_size >= WS_FLOATS * sizeof(float) && (B % ROWS_PER_BLOCK) == 0) {
        hipLaunchKernelGGL(ced_setup, dim3(32), dim3(256), 0, stream,
                           ae, ad, (float*)d_ws);
        hipLaunchKernelGGL(ced_main, dim3(B / ROWS_PER_BLOCK), dim3(512), 0, stream,
                           x, (const float*)d_ws, hw, hs, out, B);
    } else {
        hipLaunchKernelGGL(ced_fallback, dim3(B / 16), dim3(256), 0, stream,
                           x, ae, ad, hw, hs, out, B);
    }
}